// Round 1
// baseline (238.607 us; speedup 1.0000x reference)
//
#include <hip/hip_runtime.h>
#include <hip/hip_bf16.h>

#define SIZE 128

// Stable softplus: log1p(exp(x)) = max(x,0) + log1p(exp(-|x|))
__device__ __forceinline__ float softplus_f(float x) {
    return fmaxf(x, 0.0f) + log1pf(expf(-fabsf(x)));
}

__global__ __launch_bounds__(256) void probloss_kernel(
    const float4* __restrict__ inputs,    // (N, 256) as float4: 64 groups/row
    const float4* __restrict__ targets,   // (N, 128) as float4: 32 groups/row
    const float4* __restrict__ maxlv,     // (128,) as 32 float4
    const float4* __restrict__ minlv,     // (128,) as 32 float4
    float* __restrict__ out,
    int ngroups)                          // N * SIZE / 4
{
    float acc = 0.0f;
    const int stride = gridDim.x * blockDim.x;
    for (int g = blockIdx.x * blockDim.x + threadIdx.x; g < ngroups; g += stride) {
        const int r  = g >> 5;   // row (32 float4 column-groups per row)
        const int cg = g & 31;   // column group within row

        float4 m  = inputs[r * 64 + cg];        // mean: cols [0,128)
        float4 lv = inputs[r * 64 + 32 + cg];   // logvar: cols [128,256)
        float4 tg = targets[r * 32 + cg];
        float4 a  = maxlv[cg];                  // tiny, L1/L2 resident
        float4 b  = minlv[cg];

        #pragma unroll
        for (int k = 0; k < 4; ++k) {
            float mk  = (&m.x)[k];
            float lvk = (&lv.x)[k];
            float tk  = (&tg.x)[k];
            float ak  = (&a.x)[k];
            float bk  = (&b.x)[k];

            float l1 = ak - softplus_f(ak - lvk);
            float l2 = bk + softplus_f(l1 - bk);
            float d  = mk - tk;
            acc += d * d * expf(-l2) + l2;   // diff^2/var + logvar
        }
    }

    // Wave-64 reduction
    #pragma unroll
    for (int off = 32; off > 0; off >>= 1)
        acc += __shfl_down(acc, off);

    __shared__ float smem[4];   // 256 threads = 4 waves
    const int lane = threadIdx.x & 63;
    const int wid  = threadIdx.x >> 6;
    if (lane == 0) smem[wid] = acc;
    __syncthreads();
    if (threadIdx.x == 0) {
        float t = smem[0] + smem[1] + smem[2] + smem[3];
        atomicAdd(out, t);
    }
}

extern "C" void kernel_launch(void* const* d_in, const int* in_sizes, int n_in,
                              void* d_out, int out_size, void* d_ws, size_t ws_size,
                              hipStream_t stream) {
    const float4* inputs  = (const float4*)d_in[0];
    const float4* targets = (const float4*)d_in[1];
    const float4* maxlv   = (const float4*)d_in[2];
    const float4* minlv   = (const float4*)d_in[3];
    float* out = (float*)d_out;

    const int n_elems  = in_sizes[1];          // N * SIZE = 33,554,432
    const int ngroups  = n_elems / 4;          // float4 groups

    hipMemsetAsync(out, 0, sizeof(float), stream);

    const int block = 256;
    const int grid  = 2048;                    // grid-stride, ~16 iters/thread
    probloss_kernel<<<grid, block, 0, stream>>>(inputs, targets, maxlv, minlv,
                                                out, ngroups);
}

// Round 2
// 81.720 us; speedup vs baseline: 2.9198x; 2.9198x over previous
//
#include <hip/hip_runtime.h>
#include <hip/hip_bf16.h>

#define SIZE 128

__global__ __launch_bounds__(256) void probloss_kernel(
    const float4* __restrict__ inputs,    // (N, 256) as float4: 64 groups/row
    const float4* __restrict__ targets,   // (N, 128) as float4: 32 groups/row
    const float4* __restrict__ maxlv,     // (128,) as 32 float4
    const float4* __restrict__ minlv,     // (128,) as 32 float4
    float* __restrict__ out,
    int nrows)                            // N
{
    const int gtid    = blockIdx.x * blockDim.x + threadIdx.x;
    const int cg      = gtid & 31;        // fixed column group for this thread
    const int row0    = gtid >> 5;
    const int rstride = (gridDim.x * blockDim.x) >> 5;

    // Hoisted per-column constants: e^{-max_logvar}, e^{min_logvar}
    float4 a = maxlv[cg];
    float4 b = minlv[cg];
    float ena[4], eb[4];
    #pragma unroll
    for (int k = 0; k < 4; ++k) {
        ena[k] = __expf(-(&a.x)[k]);
        eb[k]  = __expf((&b.x)[k]);
    }

    float acc = 0.0f;
    for (int r = row0; r < nrows; r += rstride) {
        float4 m  = inputs[r * 64 + cg];        // mean: cols [0,128)
        float4 lv = inputs[r * 64 + 32 + cg];   // logvar: cols [128,256)
        float4 tg = targets[r * 32 + cg];

        #pragma unroll
        for (int k = 0; k < 4; ++k) {
            float lvk = (&lv.x)[k];
            float d   = (&m.x)[k] - (&tg.x)[k];
            // var = e^b + 1/(e^{-a} + e^{-lv});  l2 = log(var)
            float t   = __expf(-lvk);                       // v_exp_f32
            float s   = ena[k] + t;
            float var = eb[k] + __builtin_amdgcn_rcpf(s);   // v_rcp_f32
            float l2  = __logf(var);                        // v_log_f32
            acc += d * d * __builtin_amdgcn_rcpf(var) + l2;
        }
    }

    // Wave-64 reduction
    #pragma unroll
    for (int off = 32; off > 0; off >>= 1)
        acc += __shfl_down(acc, off);

    __shared__ float smem[4];   // 256 threads = 4 waves
    const int lane = threadIdx.x & 63;
    const int wid  = threadIdx.x >> 6;
    if (lane == 0) smem[wid] = acc;
    __syncthreads();
    if (threadIdx.x == 0) {
        float t = smem[0] + smem[1] + smem[2] + smem[3];
        atomicAdd(out, t);
    }
}

extern "C" void kernel_launch(void* const* d_in, const int* in_sizes, int n_in,
                              void* d_out, int out_size, void* d_ws, size_t ws_size,
                              hipStream_t stream) {
    const float4* inputs  = (const float4*)d_in[0];
    const float4* targets = (const float4*)d_in[1];
    const float4* maxlv   = (const float4*)d_in[2];
    const float4* minlv   = (const float4*)d_in[3];
    float* out = (float*)d_out;

    const int nrows = in_sizes[1] / SIZE;      // N = 262144

    hipMemsetAsync(out, 0, sizeof(float), stream);

    const int block = 256;
    const int grid  = 2048;    // 524288 threads -> 16 rows/thread
    probloss_kernel<<<grid, block, 0, stream>>>(inputs, targets, maxlv, minlv,
                                                out, nrows);
}